// Round 3
// baseline (549.442 us; speedup 1.0000x reference)
//
#include <hip/hip_runtime.h>
#include <cstdint>

#define S_ 197
#define D_ 768
#define H_ 12
#define B_ 2
#define SS_ (S_*S_)

// ---- output offsets (floats), concat in reference return order ----
#define O_WN   0          // (B,H,S,S)  931416
#define O_SN   931416     // (B,S,S)    77618
#define O_RWN  1009034
#define O_PLNN 1086652
#define O_PLN  1164270    // (B,S,S,D)  59610624
#define O_AM   60774894   // (B,S) 394
#define O_ARM  60775288
#define O_ARLM 60775682

// ---- workspace offsets (floats) ----
#define WS_WT   0          // W^T          768*768
#define WS_T2   589824     // T2[b][j][h][d]  2*197*12*768
#define WS_TN   4220928    // tnorm[b][h][s]  4728
#define WS_ACC  4225656    // accS[b][i][c][d] 2*197*2*768
#define WS_SMU  4830840    // smu[b][i][c]     788
#define WS_DIAG 4831628    // diagS[b][i][d]   302592
#define WS_MUI  5134220    // mu_i[b][i]       394

#define I_T 4      // i-values per main block
#define NIT 50     // ceil(197/4)
#define NC 2       // j chunks
#define JC 99      // chunk width (c0: 99, c1: 98)

// native clang vector types — required by __builtin_nontemporal_store
typedef float nf2 __attribute__((ext_vector_type(2)));
typedef float nf4 __attribute__((ext_vector_type(4)));

__device__ __forceinline__ float wred64(float v) {
#pragma unroll
  for (int off = 32; off > 0; off >>= 1) v += __shfl_xor(v, off);
  return v;
}

__device__ __forceinline__ void load12(const float* __restrict__ p, float t[12]) {
  const float4* q = (const float4*)p;
  float4 a = q[0], b = q[1], c = q[2];
  t[0]=a.x; t[1]=a.y; t[2]=a.z; t[3]=a.w;
  t[4]=b.x; t[5]=b.y; t[6]=b.z; t[7]=b.w;
  t[8]=c.x; t[9]=c.y; t[10]=c.z; t[11]=c.w;
}

// ---------------- W transpose: Wt[c][d] = W[d][c] (768x768) ----------------
__global__ __launch_bounds__(256) void kTranspose(const float* __restrict__ in,
                                                  float* __restrict__ outp) {
  __shared__ float tile[32][33];
  int x = blockIdx.x*32 + threadIdx.x;
  int y = blockIdx.y*32 + threadIdx.y;
#pragma unroll
  for (int k = 0; k < 32; k += 8) tile[threadIdx.y+k][threadIdx.x] = in[(y+k)*D_ + x];
  __syncthreads();
  x = blockIdx.y*32 + threadIdx.x;
  y = blockIdx.x*32 + threadIdx.y;
#pragma unroll
  for (int k = 0; k < 32; k += 8) outp[(y+k)*D_ + x] = tile[threadIdx.x][threadIdx.y+k];
}

// ------------- T2[b][s][h][d] = sum_v V[b,h,s,v]*W[d,h*64+v]; tnorm -------------
// 8-row s-tiles, 600 blocks = 8 XCD * 75; each XCD owns 3 consecutive bh slices
// so its Wt working set is 3*64*768*4 = 2.36 MB (L2-resident).
#define TST 8
__global__ __launch_bounds__(256) void kTransform(const float* __restrict__ V,
                                                  const float* __restrict__ Wt,
                                                  float* __restrict__ T2,
                                                  float* __restrict__ tnorm) {
  int blk = blockIdx.x;             // 600 = 8*75
  int xcd = blk & 7; int slot = blk >> 3;   // slot 0..74
  int bh = xcd*3 + (slot % 3);              // 0..23
  int st = slot / 3;                        // 0..24
  int h = bh % H_; int b = bh / H_;
  int s0 = st*TST; int ns = min(TST, S_ - s0);
  __shared__ float vt[TST*64];
  __shared__ float red[4][TST];
  int t = threadIdx.x;
  const float* Vbase = V + ((size_t)bh*S_ + s0)*64;
  for (int e = t; e < ns*64; e += 256) vt[e] = Vbase[e];
  __syncthreads();
  float acc2[TST];
#pragma unroll
  for (int s = 0; s < TST; s++) acc2[s] = 0.f;
  for (int g = 0; g < 3; g++) {
    int d = t + g*256;
    float acc[TST];
#pragma unroll
    for (int s = 0; s < TST; s++) acc[s] = 0.f;
    const float* wp = Wt + (size_t)h*64*D_ + d;
#pragma unroll 8
    for (int v = 0; v < 64; v++) {
      float wv = wp[(size_t)v*D_];
#pragma unroll
      for (int s = 0; s < TST; s++) acc[s] = fmaf(vt[s*64+v], wv, acc[s]);
    }
    for (int s = 0; s < ns; s++) {
      T2[((size_t)(b*S_ + s0+s)*H_ + h)*D_ + d] = acc[s];
      acc2[s] = fmaf(acc[s], acc[s], acc2[s]);
    }
  }
  int lane = t & 63, wq = t >> 6;
#pragma unroll
  for (int s = 0; s < TST; s++) {
    float v = wred64(acc2[s]);
    if (lane == 0) red[wq][s] = v;
  }
  __syncthreads();
  if (t < ns) {
    float v = red[0][t] + red[1][t] + red[2][t] + red[3][t];
    tnorm[bh*S_ + s0 + t] = sqrtf(v);
  }
}

// ------------- weighted_norm = |attn| * tnorm (elementwise) -------------
__global__ __launch_bounds__(256) void kWeightedNorm(const float* __restrict__ attn,
                                                     const float* __restrict__ tnorm,
                                                     float* __restrict__ outp) {
  int idx = blockIdx.x*256 + threadIdx.x;
  if (idx < B_*H_*SS_) {
    int bh = idx / SS_;
    int s = idx % S_;
    outp[O_WN + idx] = fabsf(attn[idx]) * tnorm[bh*S_ + s];
  }
}

// ------------- main fused kernel -------------
// Grid is exactly 200 = 8 XCD * 25 slots; remap so each XCD-pair owns one
// (b, j-chunk) combo -> per-XCD T2 working set = 99*12*768*4 = 3.6 MB (fits 4 MiB L2).
__global__ __launch_bounds__(768) void kMain(const float* __restrict__ attn,
                                             const float* __restrict__ hs,
                                             const float* __restrict__ lnw,
                                             const float* __restrict__ preln,
                                             const float* __restrict__ T2,
                                             float* __restrict__ outp,
                                             float* __restrict__ wsAccS,
                                             float* __restrict__ wsSmu,
                                             float* __restrict__ wsDiagS,
                                             float* __restrict__ wsMui) {
  int blk = blockIdx.x;
  int xcd = blk & 7; int slot = blk >> 3;   // slot 0..24
  int b = (xcd >> 2) & 1;                   // combo = xcd>>1: b = combo>>1
  int c = (xcd >> 1) & 1;                   //                c = combo&1
  int it = slot*2 + (xcd & 1);              // 0..49
  int i0 = it * I_T;
  int jc0 = c * JC;
  int jcE = min(jc0 + JC, S_);
  int jcW = jcE - jc0;
  int ni = min(I_T, S_ - i0);
  int tid = threadIdx.x;
  int lane = tid & 63, wv = tid >> 6;
  int dbase = lane * 12;

  __shared__ float ash[H_*I_T*JC];    // [h][i][jj]
  __shared__ float sAcc[I_T*D_];
  __shared__ float sSmu[12*I_T];

  // preload attention coefficients (coalesced over jj)
  int tot = H_*I_T*jcW;
  for (int e = tid; e < tot; e += 768) {
    int hh = e / (I_T*jcW); int rem = e - hh*(I_T*jcW);
    int ii = rem / jcW; int jj = rem - ii*jcW;
    int iG = i0 + ii;
    float v = 0.f;
    if (iG < S_) v = attn[((size_t)(b*H_ + hh)*S_ + iG)*S_ + (jc0 + jj)];
    ash[(hh*I_T + ii)*JC + jj] = v;
  }

  // per-lane setup
  float w_[12];
  load12(lnw + dbase, w_);
  float w2s_l = 0.f;
#pragma unroll
  for (int m = 0; m < 12; m++) w2s_l = fmaf(w_[m], w_[m], w2s_l);
  float w2sum = wred64(w2s_l);

  float istd[I_T];
#pragma unroll
  for (int ii = 0; ii < I_T; ii++) {
    int iG = i0 + ii;
    istd[ii] = 0.f;
    if (iG < S_) {
      float x[12];
      load12(preln + (size_t)(b*S_ + iG)*D_ + dbase, x);
      float sx = 0.f, sx2 = 0.f;
#pragma unroll
      for (int m = 0; m < 12; m++) { sx += x[m]; sx2 = fmaf(x[m], x[m], sx2); }
      sx = wred64(sx); sx2 = wred64(sx2);
      float mu = sx * (1.0f/768.0f);
      float var = sx2 * (1.0f/768.0f) - mu*mu;
      istd[ii] = 1.0f / sqrtf(var + 1e-12f);
    }
  }

  float accS[I_T][12];
#pragma unroll
  for (int ii = 0; ii < I_T; ii++)
#pragma unroll
    for (int m = 0; m < 12; m++) accS[ii][m] = 0.f;
  float smu[I_T] = {0.f, 0.f, 0.f, 0.f};

  __syncthreads();

  for (int j = jc0 + wv; j < jcE; j += 12) {
    int jj = j - jc0;
    const float* tb = T2 + (size_t)(b*S_ + j)*H_*D_ + dbase;
    float s[I_T][12];
#pragma unroll
    for (int ii = 0; ii < I_T; ii++)
#pragma unroll
      for (int m = 0; m < 12; m++) s[ii][m] = 0.f;
#pragma unroll 2
    for (int h = 0; h < H_; h++) {
      float t[12];
      load12(tb + h*D_, t);
#pragma unroll
      for (int ii = 0; ii < I_T; ii++) {
        float ah = ash[(h*I_T + ii)*JC + jj];
#pragma unroll
        for (int m = 0; m < 12; m++) s[ii][m] = fmaf(ah, t[m], s[ii][m]);
      }
    }
#pragma unroll
    for (int ii = 0; ii < I_T; ii++) {
      int iG = i0 + ii;
      if (iG < S_) {
        bool isDiag = (j == iG);
        float rw[12];
        if (isDiag) {
          float hh[12];
          load12(hs + (size_t)(b*S_ + iG)*D_ + dbase, hh);
#pragma unroll
          for (int m = 0; m < 12; m++) rw[m] = s[ii][m] + hh[m];
        } else {
#pragma unroll
          for (int m = 0; m < 12; m++) rw[m] = s[ii][m];
        }
        float ls2 = 0.f, lrw = 0.f, lrw2 = 0.f, lrww2 = 0.f, lrw2w2 = 0.f;
#pragma unroll
        for (int m = 0; m < 12; m++) {
          ls2 = fmaf(s[ii][m], s[ii][m], ls2);
          lrw += rw[m];
          float t1 = rw[m] * w_[m];
          lrww2 = fmaf(t1, w_[m], lrww2);
          lrw2 = fmaf(rw[m], rw[m], lrw2);
          lrw2w2 = fmaf(t1, t1, lrw2w2);
        }
        ls2 = wred64(ls2); lrw = wred64(lrw); lrw2 = wred64(lrw2);
        lrww2 = wred64(lrww2); lrw2w2 = wred64(lrw2w2);
        float mu = lrw * (1.0f/768.0f);
        float q = fmaf(mu*mu, w2sum, fmaf(-2.0f*mu, lrww2, lrw2w2));
        float plnn = istd[ii] * sqrtf(fmaxf(q, 0.f));
        int oIdx = (b*S_ + iG)*S_ + j;
        if (lane == 0) {
          outp[O_SN + oIdx] = sqrtf(ls2);
          outp[O_RWN + oIdx] = sqrtf(lrw2);
          outp[O_PLNN + oIdx] = plnn;
        }
        // post_ln write: base is ==8 mod 16 bytes -> peel 2 + 4 + 4 + 2.
        // Non-temporal: post_ln is write-once streaming, keep it out of L2
        // so T2 stays resident.
        float* po = outp + O_PLN + (size_t)oIdx*D_ + dbase;
        float a = istd[ii];
        float p[12];
#pragma unroll
        for (int m = 0; m < 12; m++) p[m] = (rw[m] - mu) * a * w_[m];
        __builtin_nontemporal_store((nf2){p[0], p[1]}, (nf2*)po);
        __builtin_nontemporal_store((nf4){p[2], p[3], p[4], p[5]}, (nf4*)(po + 2));
        __builtin_nontemporal_store((nf4){p[6], p[7], p[8], p[9]}, (nf4*)(po + 6));
        __builtin_nontemporal_store((nf2){p[10], p[11]}, (nf2*)(po + 10));
#pragma unroll
        for (int m = 0; m < 12; m++) accS[ii][m] += s[ii][m];
        smu[ii] += mu;
        if (isDiag) {
          float4* dp = (float4*)(wsDiagS + (size_t)(b*S_ + iG)*D_ + dbase);
          dp[0] = make_float4(s[ii][0], s[ii][1], s[ii][2],  s[ii][3]);
          dp[1] = make_float4(s[ii][4], s[ii][5], s[ii][6],  s[ii][7]);
          dp[2] = make_float4(s[ii][8], s[ii][9], s[ii][10], s[ii][11]);
          if (lane == 0) wsMui[b*S_ + iG] = mu;
        }
      }
    }
  }

  // combine per-wave accumulators
  if (lane == 0) {
#pragma unroll
    for (int ii = 0; ii < I_T; ii++) sSmu[wv*I_T + ii] = smu[ii];
  }
  for (int rr = 0; rr < 12; rr++) {
    __syncthreads();
    if (wv == rr) {
#pragma unroll
      for (int ii = 0; ii < I_T; ii++) {
        if (ii < ni) {
#pragma unroll
          for (int m = 0; m < 12; m++) {
            int a = ii*D_ + dbase + m;
            sAcc[a] = (rr == 0) ? accS[ii][m] : (sAcc[a] + accS[ii][m]);
          }
        }
      }
    }
  }
  __syncthreads();
  if (tid < ni*192) {
    int ii = tid / 192; int d4 = (tid % 192) * 4;
    float4 v = *(float4*)&sAcc[ii*D_ + d4];
    *(float4*)(wsAccS + (size_t)((b*S_ + i0 + ii)*NC + c)*D_ + d4) = v;
  }
  if (tid < ni) {
    float ss = 0.f;
#pragma unroll
    for (int wq = 0; wq < 12; wq++) ss += sSmu[wq*I_T + tid];
    wsSmu[(b*S_ + i0 + tid)*NC + c] = ss;
  }
}

// ------------- mixing-ratio finalization -------------
__global__ __launch_bounds__(256) void kMixing(const float* __restrict__ wsAccS,
                                               const float* __restrict__ wsSmu,
                                               const float* __restrict__ wsDiagS,
                                               const float* __restrict__ wsMui,
                                               const float* __restrict__ hs,
                                               const float* __restrict__ lnw,
                                               float* __restrict__ outp) {
  int bi = blockIdx.x;   // b*197 + i
  int t = threadIdx.x;
  float Smu = wsSmu[bi*2] + wsSmu[bi*2 + 1];
  float mui = wsMui[bi];
  float dmu = Smu - mui;
  float mS = 0.f, pS = 0.f, pRW = 0.f, mP = 0.f, pP = 0.f;
#pragma unroll
  for (int g = 0; g < 3; g++) {
    int d = t + g*256;
    float acc = wsAccS[(size_t)(bi*2)*D_ + d] + wsAccS[(size_t)(bi*2 + 1)*D_ + d];
    float dg = wsDiagS[(size_t)bi*D_ + d];
    float h = hs[(size_t)bi*D_ + d];
    float w = lnw[d];
    float mix = acc - dg;
    mS = fmaf(mix, mix, mS);
    pS = fmaf(dg, dg, pS);
    float drw = dg + h;
    pRW = fmaf(drw, drw, pRW);
    float mp = w * (mix - dmu);
    mP = fmaf(mp, mp, mP);
    float dp = w * (drw - mui);
    pP = fmaf(dp, dp, pP);
  }
  __shared__ float red[4][5];
  int lane = t & 63, wv = t >> 6;
  mS = wred64(mS); pS = wred64(pS); pRW = wred64(pRW); mP = wred64(mP); pP = wred64(pP);
  if (lane == 0) { red[wv][0]=mS; red[wv][1]=pS; red[wv][2]=pRW; red[wv][3]=mP; red[wv][4]=pP; }
  __syncthreads();
  if (t == 0) {
    float a0=0,a1=0,a2=0,a3=0,a4=0;
#pragma unroll
    for (int k = 0; k < 4; k++) { a0+=red[k][0]; a1+=red[k][1]; a2+=red[k][2]; a3+=red[k][3]; a4+=red[k][4]; }
    float mn = sqrtf(a0), pn = sqrtf(a1);
    outp[O_AM + bi] = mn / (mn + pn);
    float pnrw = sqrtf(a2);
    outp[O_ARM + bi] = mn / (mn + pnrw);
    float mnp = sqrtf(a3), pnp = sqrtf(a4);
    outp[O_ARLM + bi] = mnp / (mnp + pnp);
  }
}

extern "C" void kernel_launch(void* const* d_in, const int* in_sizes, int n_in,
                              void* d_out, int out_size, void* d_ws, size_t ws_size,
                              hipStream_t stream) {
  const float* hs    = (const float*)d_in[0];
  const float* attn  = (const float*)d_in[1];
  const float* V     = (const float*)d_in[2];
  const float* W     = (const float*)d_in[3];
  const float* lnw   = (const float*)d_in[4];
  const float* preln = (const float*)d_in[5];
  float* out = (float*)d_out;
  float* ws  = (float*)d_ws;

  kTranspose<<<dim3(24,24), dim3(32,8), 0, stream>>>(W, ws + WS_WT);
  kTransform<<<dim3(600), dim3(256), 0, stream>>>(V, ws + WS_WT, ws + WS_T2, ws + WS_TN);
  kWeightedNorm<<<dim3((B_*H_*SS_ + 255)/256), dim3(256), 0, stream>>>(attn, ws + WS_TN, out);
  kMain<<<dim3(B_*NIT*NC), dim3(768), 0, stream>>>(attn, hs, lnw, preln, ws + WS_T2, out,
                                                   ws + WS_ACC, ws + WS_SMU, ws + WS_DIAG, ws + WS_MUI);
  kMixing<<<dim3(B_*S_), dim3(256), 0, stream>>>(ws + WS_ACC, ws + WS_SMU, ws + WS_DIAG, ws + WS_MUI,
                                                 hs, lnw, out);
}

// Round 4
// 351.058 us; speedup vs baseline: 1.5651x; 1.5651x over previous
//
#include <hip/hip_runtime.h>
#include <cstdint>

#define S_ 197
#define D_ 768
#define H_ 12
#define B_ 2
#define SS_ (S_*S_)

// ---- output offsets (floats), concat in reference return order ----
#define O_WN   0          // (B,H,S,S)  931416
#define O_SN   931416     // (B,S,S)    77618
#define O_RWN  1009034
#define O_PLNN 1086652
#define O_PLN  1164270    // (B,S,S,D)  59610624
#define O_AM   60774894   // (B,S) 394
#define O_ARM  60775288
#define O_ARLM 60775682

// ---- workspace offsets (floats) ----
#define WS_WT   0          // W^T          768*768
#define WS_T2   589824     // T2[b][j][h][d]  2*197*12*768
#define WS_TN   4220928    // tnorm[b][h][s]  4728
#define WS_ACC  4225656    // accS[b][i][c][d] 2*197*2*768
#define WS_SMU  4830840    // smu[b][i][c]     788
#define WS_DIAG 4831628    // diagS[b][i][d]   302592
#define WS_MUI  5134220    // mu_i[b][i]       394

#define I_T 4      // i-values per main block
#define NIT 50     // ceil(197/4)
#define NC 2       // j chunks
#define JC 99      // chunk width (c0: 99, c1: 98)

__device__ __forceinline__ float wred64(float v) {
#pragma unroll
  for (int off = 32; off > 0; off >>= 1) v += __shfl_xor(v, off);
  return v;
}

__device__ __forceinline__ void load12(const float* __restrict__ p, float t[12]) {
  const float4* q = (const float4*)p;
  float4 a = q[0], b = q[1], c = q[2];
  t[0]=a.x; t[1]=a.y; t[2]=a.z; t[3]=a.w;
  t[4]=b.x; t[5]=b.y; t[6]=b.z; t[7]=b.w;
  t[8]=c.x; t[9]=c.y; t[10]=c.z; t[11]=c.w;
}

// ---------------- W transpose: Wt[c][d] = W[d][c] (768x768) ----------------
__global__ __launch_bounds__(256) void kTranspose(const float* __restrict__ in,
                                                  float* __restrict__ outp) {
  __shared__ float tile[32][33];
  int x = blockIdx.x*32 + threadIdx.x;
  int y = blockIdx.y*32 + threadIdx.y;
#pragma unroll
  for (int k = 0; k < 32; k += 8) tile[threadIdx.y+k][threadIdx.x] = in[(y+k)*D_ + x];
  __syncthreads();
  x = blockIdx.y*32 + threadIdx.x;
  y = blockIdx.x*32 + threadIdx.y;
#pragma unroll
  for (int k = 0; k < 32; k += 8) outp[(y+k)*D_ + x] = tile[threadIdx.x][threadIdx.y+k];
}

// ------------- T2[b][s][h][d] = sum_v V[b,h,s,v]*W[d,h*64+v]; tnorm -------------
// 8-row s-tiles, 600 blocks = 8 XCD * 75; each XCD owns 3 consecutive bh slices
// so its Wt working set is 3*64*768*4 = 2.36 MB (L2-resident).
#define TST 8
__global__ __launch_bounds__(256) void kTransform(const float* __restrict__ V,
                                                  const float* __restrict__ Wt,
                                                  float* __restrict__ T2,
                                                  float* __restrict__ tnorm) {
  int blk = blockIdx.x;             // 600 = 8*75
  int xcd = blk & 7; int slot = blk >> 3;   // slot 0..74
  int bh = xcd*3 + (slot % 3);              // 0..23
  int st = slot / 3;                        // 0..24
  int h = bh % H_; int b = bh / H_;
  int s0 = st*TST; int ns = min(TST, S_ - s0);
  __shared__ float vt[TST*64];
  __shared__ float red[4][TST];
  int t = threadIdx.x;
  const float* Vbase = V + ((size_t)bh*S_ + s0)*64;
  for (int e = t; e < ns*64; e += 256) vt[e] = Vbase[e];
  __syncthreads();
  float acc2[TST];
#pragma unroll
  for (int s = 0; s < TST; s++) acc2[s] = 0.f;
  for (int g = 0; g < 3; g++) {
    int d = t + g*256;
    float acc[TST];
#pragma unroll
    for (int s = 0; s < TST; s++) acc[s] = 0.f;
    const float* wp = Wt + (size_t)h*64*D_ + d;
#pragma unroll 8
    for (int v = 0; v < 64; v++) {
      float wv = wp[(size_t)v*D_];
#pragma unroll
      for (int s = 0; s < TST; s++) acc[s] = fmaf(vt[s*64+v], wv, acc[s]);
    }
    for (int s = 0; s < ns; s++) {
      T2[((size_t)(b*S_ + s0+s)*H_ + h)*D_ + d] = acc[s];
      acc2[s] = fmaf(acc[s], acc[s], acc2[s]);
    }
  }
  int lane = t & 63, wq = t >> 6;
#pragma unroll
  for (int s = 0; s < TST; s++) {
    float v = wred64(acc2[s]);
    if (lane == 0) red[wq][s] = v;
  }
  __syncthreads();
  if (t < ns) {
    float v = red[0][t] + red[1][t] + red[2][t] + red[3][t];
    tnorm[bh*S_ + s0 + t] = sqrtf(v);
  }
}

// ------------- weighted_norm = |attn| * tnorm (elementwise) -------------
__global__ __launch_bounds__(256) void kWeightedNorm(const float* __restrict__ attn,
                                                     const float* __restrict__ tnorm,
                                                     float* __restrict__ outp) {
  int idx = blockIdx.x*256 + threadIdx.x;
  if (idx < B_*H_*SS_) {
    int bh = idx / SS_;
    int s = idx % S_;
    outp[O_WN + idx] = fabsf(attn[idx]) * tnorm[bh*S_ + s];
  }
}

// ------------- main fused kernel -------------
// Grid is exactly 200 = 8 XCD * 25 slots; remap so each XCD-pair owns one
// (b, j-chunk) combo -> per-XCD T2 working set = 99*12*768*4 = 3.6 MB (fits 4 MiB L2).
// post_ln uses REGULAR cached stores: non-temporal stores caused 2.4x write
// amplification (WRITE_SIZE 585 MB vs 245 MB ideal) because sub-line stores
// bypass L2 write-combining. L2 merging is essential for the 48B/lane pattern.
__global__ __launch_bounds__(768) void kMain(const float* __restrict__ attn,
                                             const float* __restrict__ hs,
                                             const float* __restrict__ lnw,
                                             const float* __restrict__ preln,
                                             const float* __restrict__ T2,
                                             float* __restrict__ outp,
                                             float* __restrict__ wsAccS,
                                             float* __restrict__ wsSmu,
                                             float* __restrict__ wsDiagS,
                                             float* __restrict__ wsMui) {
  int blk = blockIdx.x;
  int xcd = blk & 7; int slot = blk >> 3;   // slot 0..24
  int b = (xcd >> 2) & 1;                   // combo = xcd>>1: b = combo>>1
  int c = (xcd >> 1) & 1;                   //                c = combo&1
  int it = slot*2 + (xcd & 1);              // 0..49
  int i0 = it * I_T;
  int jc0 = c * JC;
  int jcE = min(jc0 + JC, S_);
  int jcW = jcE - jc0;
  int ni = min(I_T, S_ - i0);
  int tid = threadIdx.x;
  int lane = tid & 63, wv = tid >> 6;
  int dbase = lane * 12;

  __shared__ float ash[H_*I_T*JC];    // [h][i][jj]
  __shared__ float sAcc[I_T*D_];
  __shared__ float sSmu[12*I_T];

  // preload attention coefficients (coalesced over jj)
  int tot = H_*I_T*jcW;
  for (int e = tid; e < tot; e += 768) {
    int hh = e / (I_T*jcW); int rem = e - hh*(I_T*jcW);
    int ii = rem / jcW; int jj = rem - ii*jcW;
    int iG = i0 + ii;
    float v = 0.f;
    if (iG < S_) v = attn[((size_t)(b*H_ + hh)*S_ + iG)*S_ + (jc0 + jj)];
    ash[(hh*I_T + ii)*JC + jj] = v;
  }

  // per-lane setup
  float w_[12];
  load12(lnw + dbase, w_);
  float w2s_l = 0.f;
#pragma unroll
  for (int m = 0; m < 12; m++) w2s_l = fmaf(w_[m], w_[m], w2s_l);
  float w2sum = wred64(w2s_l);

  float istd[I_T];
#pragma unroll
  for (int ii = 0; ii < I_T; ii++) {
    int iG = i0 + ii;
    istd[ii] = 0.f;
    if (iG < S_) {
      float x[12];
      load12(preln + (size_t)(b*S_ + iG)*D_ + dbase, x);
      float sx = 0.f, sx2 = 0.f;
#pragma unroll
      for (int m = 0; m < 12; m++) { sx += x[m]; sx2 = fmaf(x[m], x[m], sx2); }
      sx = wred64(sx); sx2 = wred64(sx2);
      float mu = sx * (1.0f/768.0f);
      float var = sx2 * (1.0f/768.0f) - mu*mu;
      istd[ii] = 1.0f / sqrtf(var + 1e-12f);
    }
  }

  float accS[I_T][12];
#pragma unroll
  for (int ii = 0; ii < I_T; ii++)
#pragma unroll
    for (int m = 0; m < 12; m++) accS[ii][m] = 0.f;
  float smu[I_T] = {0.f, 0.f, 0.f, 0.f};

  __syncthreads();

  for (int j = jc0 + wv; j < jcE; j += 12) {
    int jj = j - jc0;
    const float* tb = T2 + (size_t)(b*S_ + j)*H_*D_ + dbase;
    float s[I_T][12];
#pragma unroll
    for (int ii = 0; ii < I_T; ii++)
#pragma unroll
      for (int m = 0; m < 12; m++) s[ii][m] = 0.f;
#pragma unroll 2
    for (int h = 0; h < H_; h++) {
      float t[12];
      load12(tb + h*D_, t);
#pragma unroll
      for (int ii = 0; ii < I_T; ii++) {
        float ah = ash[(h*I_T + ii)*JC + jj];
#pragma unroll
        for (int m = 0; m < 12; m++) s[ii][m] = fmaf(ah, t[m], s[ii][m]);
      }
    }
#pragma unroll
    for (int ii = 0; ii < I_T; ii++) {
      int iG = i0 + ii;
      if (iG < S_) {
        bool isDiag = (j == iG);
        float rw[12];
        if (isDiag) {
          float hh[12];
          load12(hs + (size_t)(b*S_ + iG)*D_ + dbase, hh);
#pragma unroll
          for (int m = 0; m < 12; m++) rw[m] = s[ii][m] + hh[m];
        } else {
#pragma unroll
          for (int m = 0; m < 12; m++) rw[m] = s[ii][m];
        }
        float ls2 = 0.f, lrw = 0.f, lrw2 = 0.f, lrww2 = 0.f, lrw2w2 = 0.f;
#pragma unroll
        for (int m = 0; m < 12; m++) {
          ls2 = fmaf(s[ii][m], s[ii][m], ls2);
          lrw += rw[m];
          float t1 = rw[m] * w_[m];
          lrww2 = fmaf(t1, w_[m], lrww2);
          lrw2 = fmaf(rw[m], rw[m], lrw2);
          lrw2w2 = fmaf(t1, t1, lrw2w2);
        }
        ls2 = wred64(ls2); lrw = wred64(lrw); lrw2 = wred64(lrw2);
        lrww2 = wred64(lrww2); lrw2w2 = wred64(lrw2w2);
        float mu = lrw * (1.0f/768.0f);
        float q = fmaf(mu*mu, w2sum, fmaf(-2.0f*mu, lrww2, lrw2w2));
        float plnn = istd[ii] * sqrtf(fmaxf(q, 0.f));
        int oIdx = (b*S_ + iG)*S_ + j;
        if (lane == 0) {
          outp[O_SN + oIdx] = sqrtf(ls2);
          outp[O_RWN + oIdx] = sqrtf(lrw2);
          outp[O_PLNN + oIdx] = plnn;
        }
        // post_ln write: base is ==8 mod 16 bytes -> peel 2 + 4 + 4 + 2 (cached).
        float* po = outp + O_PLN + (size_t)oIdx*D_ + dbase;
        float a = istd[ii];
        float p[12];
#pragma unroll
        for (int m = 0; m < 12; m++) p[m] = (rw[m] - mu) * a * w_[m];
        *(float2*)po        = make_float2(p[0], p[1]);
        *(float4*)(po + 2)  = make_float4(p[2], p[3], p[4], p[5]);
        *(float4*)(po + 6)  = make_float4(p[6], p[7], p[8], p[9]);
        *(float2*)(po + 10) = make_float2(p[10], p[11]);
#pragma unroll
        for (int m = 0; m < 12; m++) accS[ii][m] += s[ii][m];
        smu[ii] += mu;
        if (isDiag) {
          float4* dp = (float4*)(wsDiagS + (size_t)(b*S_ + iG)*D_ + dbase);
          dp[0] = make_float4(s[ii][0], s[ii][1], s[ii][2],  s[ii][3]);
          dp[1] = make_float4(s[ii][4], s[ii][5], s[ii][6],  s[ii][7]);
          dp[2] = make_float4(s[ii][8], s[ii][9], s[ii][10], s[ii][11]);
          if (lane == 0) wsMui[b*S_ + iG] = mu;
        }
      }
    }
  }

  // combine per-wave accumulators
  if (lane == 0) {
#pragma unroll
    for (int ii = 0; ii < I_T; ii++) sSmu[wv*I_T + ii] = smu[ii];
  }
  for (int rr = 0; rr < 12; rr++) {
    __syncthreads();
    if (wv == rr) {
#pragma unroll
      for (int ii = 0; ii < I_T; ii++) {
        if (ii < ni) {
#pragma unroll
          for (int m = 0; m < 12; m++) {
            int a = ii*D_ + dbase + m;
            sAcc[a] = (rr == 0) ? accS[ii][m] : (sAcc[a] + accS[ii][m]);
          }
        }
      }
    }
  }
  __syncthreads();
  if (tid < ni*192) {
    int ii = tid / 192; int d4 = (tid % 192) * 4;
    float4 v = *(float4*)&sAcc[ii*D_ + d4];
    *(float4*)(wsAccS + (size_t)((b*S_ + i0 + ii)*NC + c)*D_ + d4) = v;
  }
  if (tid < ni) {
    float ss = 0.f;
#pragma unroll
    for (int wq = 0; wq < 12; wq++) ss += sSmu[wq*I_T + tid];
    wsSmu[(b*S_ + i0 + tid)*NC + c] = ss;
  }
}

// ------------- mixing-ratio finalization -------------
__global__ __launch_bounds__(256) void kMixing(const float* __restrict__ wsAccS,
                                               const float* __restrict__ wsSmu,
                                               const float* __restrict__ wsDiagS,
                                               const float* __restrict__ wsMui,
                                               const float* __restrict__ hs,
                                               const float* __restrict__ lnw,
                                               float* __restrict__ outp) {
  int bi = blockIdx.x;   // b*197 + i
  int t = threadIdx.x;
  float Smu = wsSmu[bi*2] + wsSmu[bi*2 + 1];
  float mui = wsMui[bi];
  float dmu = Smu - mui;
  float mS = 0.f, pS = 0.f, pRW = 0.f, mP = 0.f, pP = 0.f;
#pragma unroll
  for (int g = 0; g < 3; g++) {
    int d = t + g*256;
    float acc = wsAccS[(size_t)(bi*2)*D_ + d] + wsAccS[(size_t)(bi*2 + 1)*D_ + d];
    float dg = wsDiagS[(size_t)bi*D_ + d];
    float h = hs[(size_t)bi*D_ + d];
    float w = lnw[d];
    float mix = acc - dg;
    mS = fmaf(mix, mix, mS);
    pS = fmaf(dg, dg, pS);
    float drw = dg + h;
    pRW = fmaf(drw, drw, pRW);
    float mp = w * (mix - dmu);
    mP = fmaf(mp, mp, mP);
    float dp = w * (drw - mui);
    pP = fmaf(dp, dp, pP);
  }
  __shared__ float red[4][5];
  int lane = t & 63, wv = t >> 6;
  mS = wred64(mS); pS = wred64(pS); pRW = wred64(pRW); mP = wred64(mP); pP = wred64(pP);
  if (lane == 0) { red[wv][0]=mS; red[wv][1]=pS; red[wv][2]=pRW; red[wv][3]=mP; red[wv][4]=pP; }
  __syncthreads();
  if (t == 0) {
    float a0=0,a1=0,a2=0,a3=0,a4=0;
#pragma unroll
    for (int k = 0; k < 4; k++) { a0+=red[k][0]; a1+=red[k][1]; a2+=red[k][2]; a3+=red[k][3]; a4+=red[k][4]; }
    float mn = sqrtf(a0), pn = sqrtf(a1);
    outp[O_AM + bi] = mn / (mn + pn);
    float pnrw = sqrtf(a2);
    outp[O_ARM + bi] = mn / (mn + pnrw);
    float mnp = sqrtf(a3), pnp = sqrtf(a4);
    outp[O_ARLM + bi] = mnp / (mnp + pnp);
  }
}

extern "C" void kernel_launch(void* const* d_in, const int* in_sizes, int n_in,
                              void* d_out, int out_size, void* d_ws, size_t ws_size,
                              hipStream_t stream) {
  const float* hs    = (const float*)d_in[0];
  const float* attn  = (const float*)d_in[1];
  const float* V     = (const float*)d_in[2];
  const float* W     = (const float*)d_in[3];
  const float* lnw   = (const float*)d_in[4];
  const float* preln = (const float*)d_in[5];
  float* out = (float*)d_out;
  float* ws  = (float*)d_ws;

  kTranspose<<<dim3(24,24), dim3(32,8), 0, stream>>>(W, ws + WS_WT);
  kTransform<<<dim3(600), dim3(256), 0, stream>>>(V, ws + WS_WT, ws + WS_T2, ws + WS_TN);
  kWeightedNorm<<<dim3((B_*H_*SS_ + 255)/256), dim3(256), 0, stream>>>(attn, ws + WS_TN, out);
  kMain<<<dim3(B_*NIT*NC), dim3(768), 0, stream>>>(attn, hs, lnw, preln, ws + WS_T2, out,
                                                   ws + WS_ACC, ws + WS_SMU, ws + WS_DIAG, ws + WS_MUI);
  kMixing<<<dim3(B_*S_), dim3(256), 0, stream>>>(ws + WS_ACC, ws + WS_SMU, ws + WS_DIAG, ws + WS_MUI,
                                                 hs, lnw, out);
}